// Round 2
// baseline (2404.048 us; speedup 1.0000x reference)
//
#include <hip/hip_runtime.h>

typedef __attribute__((ext_vector_type(8))) short bf16x8;
typedef __attribute__((ext_vector_type(4))) float f32x4;

__device__ __forceinline__ float b2f(short s) {
  return __uint_as_float(((unsigned int)(unsigned short)s) << 16);
}
__device__ __forceinline__ short f2b(float f) {
  unsigned int u = __float_as_uint(f);
  unsigned int r = (u + 0x7fffu + ((u >> 16) & 1u)) >> 16;
  return (short)(unsigned short)r;
}

#define GLOAD16(g, l) __builtin_amdgcn_global_load_lds( \
    (const __attribute__((address_space(1))) void*)(g),  \
    (__attribute__((address_space(3))) void*)(l), 16, 0, 0)

// ---------------- f32 -> bf16 convert ----------------
__global__ __launch_bounds__(256) void cvt_kernel(const float* __restrict__ src,
                                                  short* __restrict__ dst, long n) {
  long i = ((long)blockIdx.x * 256 + threadIdx.x) * 8;
  long stride = (long)gridDim.x * 256 * 8;
  for (; i + 8 <= n; i += stride) {
    float4 a = *(const float4*)(src + i);
    float4 b = *(const float4*)(src + i + 4);
    bf16x8 o;
    o[0] = f2b(a.x); o[1] = f2b(a.y); o[2] = f2b(a.z); o[3] = f2b(a.w);
    o[4] = f2b(b.x); o[5] = f2b(b.y); o[6] = f2b(b.z); o[7] = f2b(b.w);
    *(bf16x8*)(dst + i) = o;
  }
}

// ---------------- gather next-token embeddings, shift, convert ----------------
__global__ __launch_bounds__(256) void gather_kernel(const float* __restrict__ emb,
    const int* __restrict__ ids, short* __restrict__ sh) {
  const int token = blockIdx.x;          // 0..4095, token = b*2048 + s
  const int s = token & 2047;
  const long dst = (long)token * 4096;
  const int row = (s == 2047) ? -1 : ids[token + 1];
  for (int it = 0; it < 2; ++it) {
    const int e = it * 2048 + threadIdx.x * 8;
    bf16x8 o;
    if (row < 0) {
      #pragma unroll
      for (int j = 0; j < 8; ++j) o[j] = 0;
    } else {
      float4 a = *(const float4*)(emb + (long)row * 4096 + e);
      float4 b = *(const float4*)(emb + (long)row * 4096 + e + 4);
      o[0] = f2b(a.x); o[1] = f2b(a.y); o[2] = f2b(a.z); o[3] = f2b(a.w);
      o[4] = f2b(b.x); o[5] = f2b(b.y); o[6] = f2b(b.z); o[7] = f2b(b.w);
    }
    *(bf16x8*)(sh + dst + e) = o;
  }
}

// ---------------- init_A [4096][16] f32 -> [16][4096] bf16 ----------------
__global__ __launch_bounds__(256) void tposeA_kernel(const float* __restrict__ A,
                                                     short* __restrict__ At) {
  const int h = blockIdx.x * 256 + threadIdx.x;
  #pragma unroll
  for (int r = 0; r < 16; ++r) At[(long)r * 4096 + h] = f2b(A[(long)h * 16 + r]);
}

// ---------------- bf16 MFMA GEMM: C[M,N] = A[M,K] @ B[N,K]^T ----------------
// 128x128 tile, BK=32, 4 waves (2x2 of 64x64), global_load_lds staging with
// granule-transposed LDS layout: granule p = kchunk*128 + row (16B granules).
template <int OUTBF16>
__global__ __launch_bounds__(256) void gemm_bt(const short* __restrict__ A,
    const short* __restrict__ B, void* __restrict__ C, int M, int N, int K) {
  __shared__ short lds[8192];  // A bytes [0,8192), B bytes [8192,16384)
  const int tid = threadIdx.x;
  const int lane = tid & 63;
  const int wid = tid >> 6;
  const int wr = wid >> 1, wc = wid & 1;
  const long m0 = (long)blockIdx.y * 128;
  const long n0 = (long)blockIdx.x * 128;

  // staging: thread t loads granules p=t (kchunk=t>>7) and p=t+256 (kchunk+2), row=t&127
  const int r0 = tid & 127;
  const int c0 = tid >> 7;
  const short* ag = A + (m0 + r0) * (long)K + c0 * 8;
  const short* bg = B + (n0 + r0) * (long)K + c0 * 8;
  char* la0 = (char*)lds + tid * 16;
  char* la1 = la0 + 4096;
  char* lb0 = la0 + 8192;
  char* lb1 = la0 + 12288;

  // fragment ds_read byte offsets: granule (lane>>4)*128 + row
  int aoff[4], boff[4];
  #pragma unroll
  for (int i = 0; i < 4; ++i) {
    aoff[i] = (((lane >> 4) * 128) + wr * 64 + i * 16 + (lane & 15)) * 16;
    boff[i] = (((lane >> 4) * 128) + wc * 64 + i * 16 + (lane & 15)) * 16 + 8192;
  }

  f32x4 acc[4][4];
  #pragma unroll
  for (int mi = 0; mi < 4; ++mi)
    #pragma unroll
    for (int ni = 0; ni < 4; ++ni) {
      acc[mi][ni][0] = 0.f; acc[mi][ni][1] = 0.f;
      acc[mi][ni][2] = 0.f; acc[mi][ni][3] = 0.f;
    }

  for (int kt = 0; kt < K; kt += 32) {
    __syncthreads();
    GLOAD16(ag, la0);
    GLOAD16(ag + 16, la1);
    GLOAD16(bg, lb0);
    GLOAD16(bg + 16, lb1);
    ag += 32; bg += 32;
    __syncthreads();
    bf16x8 av[4], bv[4];
    #pragma unroll
    for (int i = 0; i < 4; ++i) av[i] = *(const bf16x8*)((const char*)lds + aoff[i]);
    #pragma unroll
    for (int i = 0; i < 4; ++i) bv[i] = *(const bf16x8*)((const char*)lds + boff[i]);
    #pragma unroll
    for (int mi = 0; mi < 4; ++mi)
      #pragma unroll
      for (int ni = 0; ni < 4; ++ni)
        acc[mi][ni] = __builtin_amdgcn_mfma_f32_16x16x32_bf16(av[mi], bv[ni],
                                                              acc[mi][ni], 0, 0, 0);
  }

  const int orow = (lane >> 4) * 4;
  const int ocol = lane & 15;
  #pragma unroll
  for (int mi = 0; mi < 4; ++mi)
    #pragma unroll
    for (int ni = 0; ni < 4; ++ni)
      #pragma unroll
      for (int j = 0; j < 4; ++j) {
        const long row = m0 + wr * 64 + mi * 16 + orow + j;
        const long col = n0 + wc * 64 + ni * 16 + ocol;
        if (OUTBF16) ((short*)C)[row * N + col] = f2b(acc[mi][ni][j]);
        else         ((float*)C)[row * N + col] = acc[mi][ni][j];
      }
}

// ---------------- skinny GEMM: out[t][16] = X[t,:] @ W[16,K]^T ----------------
// one wave per token; wStride!=0 selects per-chunk W (B_eff)
__global__ __launch_bounds__(256) void rowgemm16(const short* __restrict__ X,
    const short* __restrict__ W, float* __restrict__ out, int K, long wStride) {
  const int lane = threadIdx.x & 63;
  const int token = blockIdx.x * 4 + (threadIdx.x >> 6);
  const short* Xr = X + (long)token * K;
  const short* Wr = W + (long)(token >> 6) * wStride;
  float acc[16];
  #pragma unroll
  for (int r = 0; r < 16; ++r) acc[r] = 0.f;
  const int nIter = (K + 511) >> 9;
  for (int i = 0; i < nIter; ++i) {
    const int k = i * 512 + lane * 8;
    if (k + 8 <= K) {
      bf16x8 xv = *(const bf16x8*)(Xr + k);
      float xf[8];
      #pragma unroll
      for (int j = 0; j < 8; ++j) xf[j] = b2f(xv[j]);
      #pragma unroll
      for (int r = 0; r < 16; ++r) {
        bf16x8 wv = *(const bf16x8*)(Wr + (long)r * K + k);
        #pragma unroll
        for (int j = 0; j < 8; ++j) acc[r] = fmaf(xf[j], b2f(wv[j]), acc[r]);
      }
    }
  }
  #pragma unroll
  for (int r = 0; r < 16; ++r) {
    float v = acc[r];
    #pragma unroll
    for (int off = 32; off > 0; off >>= 1) v += __shfl_xor(v, off, 64);
    acc[r] = v;
  }
  if (lane == 0) {
    #pragma unroll
    for (int r = 0; r < 16; ++r) out[(long)token * 16 + r] = acc[r];
  }
}

// ---------------- fused dA + exclusive cumsum -> A_eff (bf16) ----------------
// A_eff[chunk][h][r] = initA[h][r] - 0.02 * sum_{m<n} dA_m[h][r]
__global__ __launch_bounds__(256) void aeff_kernel(const short* __restrict__ V,
    const float* __restrict__ projin, const float* __restrict__ initA,
    short* __restrict__ Aeff) {
  const int b = blockIdx.y;
  const int h = blockIdx.x * 256 + threadIdx.x;
  __shared__ float pin[1024];
  float acc[16], a0[16];
  #pragma unroll
  for (int r = 0; r < 16; ++r) { acc[r] = 0.f; a0[r] = initA[(long)h * 16 + r]; }
  for (int n = 0; n < 32; ++n) {
    const int chunk = b * 32 + n;
    __syncthreads();
    #pragma unroll
    for (int i = 0; i < 4; ++i)
      pin[i * 256 + threadIdx.x] = projin[(long)chunk * 1024 + i * 256 + threadIdx.x];
    __syncthreads();
    bf16x8 w0, w1;
    #pragma unroll
    for (int r = 0; r < 8; ++r) {
      w0[r] = f2b(a0[r] - 0.02f * acc[r]);
      w1[r] = f2b(a0[r + 8] - 0.02f * acc[r + 8]);
    }
    short* dst = Aeff + ((long)chunk * 4096 + h) * 16;
    *(bf16x8*)dst = w0;
    *(bf16x8*)(dst + 8) = w1;
    for (int c = 0; c < 64; ++c) {
      const float v = b2f(V[((long)(chunk * 64 + c)) * 4096 + h]);
      #pragma unroll
      for (int r = 0; r < 16; ++r) acc[r] = fmaf(v, pin[c * 16 + r], acc[r]);
    }
  }
}

// ---------------- fused dB + exclusive cumsum -> B_eff (bf16) ----------------
// B_eff[chunk][r][k] = initB[r][k] - 0.02 * sum_{m<n} dB_m[r][k]
__global__ __launch_bounds__(256) void beff_kernel(const short* __restrict__ X,
    const float* __restrict__ projerr, const float* __restrict__ initB,
    short* __restrict__ Beff) {
  const int b = blockIdx.y;
  const int k = blockIdx.x * 256 + threadIdx.x;  // 43*256 == 11008 exactly
  __shared__ float pe[1024];
  float acc[16], b0[16];
  #pragma unroll
  for (int r = 0; r < 16; ++r) { acc[r] = 0.f; b0[r] = initB[(long)r * 11008 + k]; }
  for (int n = 0; n < 32; ++n) {
    const int chunk = b * 32 + n;
    __syncthreads();
    #pragma unroll
    for (int i = 0; i < 4; ++i)
      pe[i * 256 + threadIdx.x] = projerr[(long)chunk * 1024 + i * 256 + threadIdx.x];
    __syncthreads();
    #pragma unroll
    for (int r = 0; r < 16; ++r)
      Beff[((long)chunk * 16 + r) * 11008 + k] = f2b(b0[r] - 0.02f * acc[r]);
    for (int c = 0; c < 64; ++c) {
      const float xv = b2f(X[((long)(chunk * 64 + c)) * 11008 + k]);
      #pragma unroll
      for (int r = 0; r < 16; ++r) acc[r] = fmaf(xv, pe[c * 16 + r], acc[r]);
    }
  }
}

// ---------------- out(f32) = base + 2 * mid @ A_eff^T ----------------
__global__ __launch_bounds__(256) void final_kernel(const float* __restrict__ base,
    const float* __restrict__ mid, const short* __restrict__ Aeff,
    float* __restrict__ out) {
  const int token = blockIdx.x;
  const int chunk = token >> 6;
  __shared__ float m[16];
  if (threadIdx.x < 16) m[threadIdx.x] = mid[(long)token * 16 + threadIdx.x];
  __syncthreads();
  float mf[16];
  #pragma unroll
  for (int r = 0; r < 16; ++r) mf[r] = m[r];
  for (int it = 0; it < 16; ++it) {
    const int h = it * 256 + threadIdx.x;
    const short* ar = Aeff + ((long)chunk * 4096 + h) * 16;
    bf16x8 a0 = *(const bf16x8*)ar;
    bf16x8 a1 = *(const bf16x8*)(ar + 8);
    float s = 0.f;
    #pragma unroll
    for (int j = 0; j < 8; ++j) {
      s = fmaf(mf[j], b2f(a0[j]), s);
      s = fmaf(mf[j + 8], b2f(a1[j]), s);
    }
    out[(long)token * 4096 + h] = base[(long)token * 4096 + h] + 2.0f * s;
  }
}

extern "C" void kernel_launch(void* const* d_in, const int* in_sizes, int n_in,
                              void* d_out, int out_size, void* d_ws, size_t ws_size,
                              hipStream_t stream) {
  const float* x     = (const float*)d_in[0];   // [2,2048,11008]
  const float* Wbase = (const float*)d_in[1];   // [4096,11008]
  const float* emb   = (const float*)d_in[2];   // [32000,4096]
  const float* Wproj = (const float*)d_in[3];   // [4096,4096]
  const float* initA = (const float*)d_in[4];   // [4096,16]
  const float* initB = (const float*)d_in[5];   // [16,11008]
  const int*   ids   = (const int*)d_in[6];     // [2,2048]
  float* outp = (float*)d_out;                  // f32 [2,2048,4096]

  char* p = (char*)d_ws;
  short* xb   = (short*)p; p += 90177536L;   // x bf16
  short* Wb   = (short*)p; p += 90177536L;   // W_base bf16
  short* Wpb  = (short*)p; p += 33554432L;   // W_proj bf16
  short* shb  = (short*)p; p += 33554432L;   // shifted embeds bf16
  short* Vb   = (short*)p; p += 33554432L;   // V bf16
  float* base = (float*)p; p += 67108864L;   // base_out f32
  short* iBb  = (short*)p; p += 352256L;     // init_B bf16
  short* iAt  = (short*)p; p += 131072L;     // init_A^T bf16 [16][4096]
  float* pin  = (float*)p; p += 262144L;     // proj_in f32 [4096][16]
  float* per  = (float*)p; p += 262144L;     // proj_err f32 [4096][16]
  float* mid  = (float*)p; p += 262144L;     // mid f32 [4096][16]
  short* Aeff = (short*)p; p += 8388608L;    // [64][4096][16] bf16
  short* Beff = (short*)p; p += 22544384L;   // [64][16][11008] bf16

  cvt_kernel<<<2048, 256, 0, stream>>>(x, xb, 45088768L);
  cvt_kernel<<<2048, 256, 0, stream>>>(Wbase, Wb, 45088768L);
  cvt_kernel<<<2048, 256, 0, stream>>>(Wproj, Wpb, 16777216L);
  cvt_kernel<<<86, 256, 0, stream>>>(initB, iBb, 176128L);
  tposeA_kernel<<<16, 256, 0, stream>>>(initA, iAt);
  gather_kernel<<<4096, 256, 0, stream>>>(emb, ids, shb);

  gemm_bt<1><<<dim3(32, 32), 256, 0, stream>>>(shb, Wpb, (void*)Vb, 4096, 4096, 4096);
  gemm_bt<0><<<dim3(32, 32), 256, 0, stream>>>(xb, Wb, (void*)base, 4096, 4096, 11008);

  rowgemm16<<<1024, 256, 0, stream>>>(xb, iBb, pin, 11008, 0L);   // proj_in
  rowgemm16<<<1024, 256, 0, stream>>>(Vb, iAt, per, 4096, 0L);    // proj_err

  aeff_kernel<<<dim3(16, 2), 256, 0, stream>>>(Vb, pin, initA, Aeff);
  beff_kernel<<<dim3(43, 2), 256, 0, stream>>>(xb, per, initB, Beff);

  rowgemm16<<<1024, 256, 0, stream>>>(xb, Beff, mid, 11008, 176128L);  // mid
  final_kernel<<<4096, 256, 0, stream>>>(base, mid, Aeff, outp);
}

// Round 3
// 1798.474 us; speedup vs baseline: 1.3367x; 1.3367x over previous
//
#include <hip/hip_runtime.h>

typedef __attribute__((ext_vector_type(8))) short bf16x8;
typedef __attribute__((ext_vector_type(4))) float f32x4;

__device__ __forceinline__ float b2f(short s) {
  return __uint_as_float(((unsigned int)(unsigned short)s) << 16);
}
__device__ __forceinline__ short f2b(float f) {
  unsigned int u = __float_as_uint(f);
  unsigned int r = (u + 0x7fffu + ((u >> 16) & 1u)) >> 16;
  return (short)(unsigned short)r;
}

#define GLOAD16(g, l) __builtin_amdgcn_global_load_lds( \
    (const __attribute__((address_space(1))) void*)(g),  \
    (__attribute__((address_space(3))) void*)(l), 16, 0, 0)

// ---------------- f32 -> bf16 convert ----------------
__global__ __launch_bounds__(256) void cvt_kernel(const float* __restrict__ src,
                                                  short* __restrict__ dst, long n) {
  long i = ((long)blockIdx.x * 256 + threadIdx.x) * 8;
  long stride = (long)gridDim.x * 256 * 8;
  for (; i + 8 <= n; i += stride) {
    float4 a = *(const float4*)(src + i);
    float4 b = *(const float4*)(src + i + 4);
    bf16x8 o;
    o[0] = f2b(a.x); o[1] = f2b(a.y); o[2] = f2b(a.z); o[3] = f2b(a.w);
    o[4] = f2b(b.x); o[5] = f2b(b.y); o[6] = f2b(b.z); o[7] = f2b(b.w);
    *(bf16x8*)(dst + i) = o;
  }
}

// ---------------- gather next-token embeddings, shift, convert ----------------
__global__ __launch_bounds__(256) void gather_kernel(const float* __restrict__ emb,
    const int* __restrict__ ids, short* __restrict__ sh) {
  const int token = blockIdx.x;          // 0..4095, token = b*2048 + s
  const int s = token & 2047;
  const long dst = (long)token * 4096;
  const int row = (s == 2047) ? -1 : ids[token + 1];
  for (int it = 0; it < 2; ++it) {
    const int e = it * 2048 + threadIdx.x * 8;
    bf16x8 o;
    if (row < 0) {
      #pragma unroll
      for (int j = 0; j < 8; ++j) o[j] = 0;
    } else {
      float4 a = *(const float4*)(emb + (long)row * 4096 + e);
      float4 b = *(const float4*)(emb + (long)row * 4096 + e + 4);
      o[0] = f2b(a.x); o[1] = f2b(a.y); o[2] = f2b(a.z); o[3] = f2b(a.w);
      o[4] = f2b(b.x); o[5] = f2b(b.y); o[6] = f2b(b.z); o[7] = f2b(b.w);
    }
    *(bf16x8*)(sh + dst + e) = o;
  }
}

// ---------------- init_A [4096][16] f32 -> [16][4096] bf16 ----------------
__global__ __launch_bounds__(256) void tposeA_kernel(const float* __restrict__ A,
                                                     short* __restrict__ At) {
  const int h = blockIdx.x * 256 + threadIdx.x;
  #pragma unroll
  for (int r = 0; r < 16; ++r) At[(long)r * 4096 + h] = f2b(A[(long)h * 16 + r]);
}

// ======== deep-pipelined 256x256 MFMA GEMM: C[M,N] = A[M,K] @ B[N,K]^T ========
// BK=64, 8 waves (2M x 4N, each 128x64 out), double-buffered LDS (128 KiB),
// chunked staging (8 chunks/K-tile, 2/phase), single vmcnt(6) per K-tile at
// phase 3, raw barriers, lgkmcnt(0)+sched_barrier before 16-MFMA clusters,
// setprio around MFMA, granule-transposed LDS (16B granule = kchunk*256+row).
template <int OUTBF16>
__global__ __launch_bounds__(512, 2) void gemm8p(const short* __restrict__ A,
    const short* __restrict__ B, void* __restrict__ C, int M, int N, int Kd) {
  __shared__ short lds[65536];  // 128 KiB: buf0 [A 32K | B 32K], buf1 same
  const int tid = threadIdx.x;
  const int lane = tid & 63;
  const int wid = tid >> 6;        // 0..7
  const int wr = wid >> 2;         // 0..1  (M half)
  const int wcn = wid & 3;         // 0..3  (N quarter)
  const int l15 = lane & 15, l4 = lane >> 4;

  // XCD-aware bijective swizzle (grid size is a multiple of 8 here: 256)
  const int nbx = N >> 8;
  const int nwg = gridDim.x;
  const int cpx = nwg >> 3;
  const int wg = ((int)blockIdx.x & 7) * cpx + ((int)blockIdx.x >> 3);
  const long m0 = (long)(wg / nbx) * 256;
  const long n0 = (long)(wg % nbx) * 256;

  const int NT = Kd >> 6;  // K-tiles of 64 (K divisible by 64 for our shapes)

  const short* Ag = A + (m0 + lane) * (long)Kd + wid * 8;
  const short* Bg = B + (n0 + lane) * (long)Kd + wid * 8;

#define STAGE_A(b, kt, c) GLOAD16(Ag + (long)(c) * 64 * Kd + (long)(kt) * 64, \
    (char*)lds + (b) * 65536 + wid * 4096 + (c) * 1024 + lane * 16)
#define STAGE_B(b, kt, c) GLOAD16(Bg + (long)(c) * 64 * Kd + (long)(kt) * 64, \
    (char*)lds + (b) * 65536 + 32768 + wid * 4096 + (c) * 1024 + lane * 16)

  // ds_read base offsets (bytes, within current buffer)
  const int aoff0 = (l4 * 256 + wr * 32 + l15) * 16;
  const int boff0 = (l4 * 256 + wcn * 64 + l15) * 16 + 32768;

  f32x4 acc[8][4];
  #pragma unroll
  for (int m = 0; m < 8; ++m)
    #pragma unroll
    for (int n = 0; n < 4; ++n) {
      acc[m][n][0] = 0.f; acc[m][n][1] = 0.f;
      acc[m][n][2] = 0.f; acc[m][n][3] = 0.f;
    }

  // -------- prologue: tile 0 complete (8 chunks) + tile 1 chunks 0..2 --------
  STAGE_A(0, 0, 0); STAGE_B(0, 0, 0);
  STAGE_A(0, 0, 1); STAGE_B(0, 0, 1);
  STAGE_A(0, 0, 2); STAGE_B(0, 0, 2);
  STAGE_A(0, 0, 3); STAGE_B(0, 0, 3);
  STAGE_A(1, 1, 0); STAGE_B(1, 1, 0);
  STAGE_A(1, 1, 1); STAGE_B(1, 1, 1);
  STAGE_A(1, 1, 2); STAGE_B(1, 1, 2);
  asm volatile("s_waitcnt vmcnt(6)" ::: "memory");
  __builtin_amdgcn_s_barrier();
  asm volatile("" ::: "memory");

  for (int t = 0; t < NT; ++t) {
    const int cur = t & 1;
    const int tn1 = (t + 1 < NT) ? t + 1 : 0;   // wrap -> garbage stage, safe slot
    const int tn2 = (t + 2 < NT) ? t + 2 : 0;
    const char* pa = (const char*)lds + cur * 65536 + aoff0;
    const char* pb = (const char*)lds + cur * 65536 + boff0;
    bf16x8 bv[4][2];
    #pragma unroll
    for (int q = 0; q < 4; ++q) {
      // --- ds-read this phase's fragments (data validated at prev tile ph3) ---
      bf16x8 av[2][2];
      if (q == 0) {
        #pragma unroll
        for (int nf = 0; nf < 4; ++nf) {
          bv[nf][0] = *(const bf16x8*)(pb + nf * 256);
          bv[nf][1] = *(const bf16x8*)(pb + nf * 256 + 16384);
        }
      }
      #pragma unroll
      for (int sub = 0; sub < 2; ++sub) {
        av[sub][0] = *(const bf16x8*)(pa + q * 1024 + sub * 256);
        av[sub][1] = *(const bf16x8*)(pa + q * 1024 + sub * 256 + 16384);
      }
      // --- stage 2 chunks (prefetch ~1.75 tiles ahead) ---
      if (q == 0) { STAGE_A(cur ^ 1, tn1, 3); STAGE_B(cur ^ 1, tn1, 3); }
      else        { STAGE_A(cur, tn2, q - 1); STAGE_B(cur, tn2, q - 1); }
      // --- tile-boundary wait: validate tile t+1 before its phase-0 reads ---
      if (q == 3) asm volatile("s_waitcnt vmcnt(6)" ::: "memory");
      __builtin_amdgcn_s_barrier();
      asm volatile("s_waitcnt lgkmcnt(0)" ::: "memory");
      __builtin_amdgcn_sched_barrier(0);
      __builtin_amdgcn_s_setprio(1);
      #pragma unroll
      for (int sub = 0; sub < 2; ++sub)
        #pragma unroll
        for (int nf = 0; nf < 4; ++nf) {
          acc[q * 2 + sub][nf] = __builtin_amdgcn_mfma_f32_16x16x32_bf16(
              av[sub][0], bv[nf][0], acc[q * 2 + sub][nf], 0, 0, 0);
          acc[q * 2 + sub][nf] = __builtin_amdgcn_mfma_f32_16x16x32_bf16(
              av[sub][1], bv[nf][1], acc[q * 2 + sub][nf], 0, 0, 0);
        }
      __builtin_amdgcn_s_setprio(0);
      __builtin_amdgcn_s_barrier();
      asm volatile("" ::: "memory");
    }
  }
#undef STAGE_A
#undef STAGE_B

  // -------- epilogue: C write --------
  #pragma unroll
  for (int q = 0; q < 4; ++q)
    #pragma unroll
    for (int sub = 0; sub < 2; ++sub)
      #pragma unroll
      for (int nf = 0; nf < 4; ++nf)
        #pragma unroll
        for (int j = 0; j < 4; ++j) {
          const long row = m0 + q * 64 + wr * 32 + sub * 16 + l4 * 4 + j;
          const long col = n0 + wcn * 64 + nf * 16 + l15;
          if (OUTBF16) ((short*)C)[row * N + col] = f2b(acc[q * 2 + sub][nf][j]);
          else         ((float*)C)[row * N + col] = acc[q * 2 + sub][nf][j];
        }
}

// ---------------- skinny GEMM: out[t][16] = X[t,:] @ W[16,K]^T ----------------
__global__ __launch_bounds__(256) void rowgemm16(const short* __restrict__ X,
    const short* __restrict__ W, float* __restrict__ out, int K, long wStride) {
  const int lane = threadIdx.x & 63;
  const int token = blockIdx.x * 4 + (threadIdx.x >> 6);
  const short* Xr = X + (long)token * K;
  const short* Wr = W + (long)(token >> 6) * wStride;
  float acc[16];
  #pragma unroll
  for (int r = 0; r < 16; ++r) acc[r] = 0.f;
  const int nIter = (K + 511) >> 9;
  for (int i = 0; i < nIter; ++i) {
    const int k = i * 512 + lane * 8;
    if (k + 8 <= K) {
      bf16x8 xv = *(const bf16x8*)(Xr + k);
      float xf[8];
      #pragma unroll
      for (int j = 0; j < 8; ++j) xf[j] = b2f(xv[j]);
      #pragma unroll
      for (int r = 0; r < 16; ++r) {
        bf16x8 wv = *(const bf16x8*)(Wr + (long)r * K + k);
        #pragma unroll
        for (int j = 0; j < 8; ++j) acc[r] = fmaf(xf[j], b2f(wv[j]), acc[r]);
      }
    }
  }
  #pragma unroll
  for (int r = 0; r < 16; ++r) {
    float v = acc[r];
    #pragma unroll
    for (int off = 32; off > 0; off >>= 1) v += __shfl_xor(v, off, 64);
    acc[r] = v;
  }
  if (lane == 0) {
    #pragma unroll
    for (int r = 0; r < 16; ++r) out[(long)token * 16 + r] = acc[r];
  }
}

// ---------------- fused dA + exclusive cumsum -> A_eff (bf16) ----------------
__global__ __launch_bounds__(256) void aeff_kernel(const short* __restrict__ V,
    const float* __restrict__ projin, const float* __restrict__ initA,
    short* __restrict__ Aeff) {
  const int b = blockIdx.y;
  const int h = blockIdx.x * 256 + threadIdx.x;
  __shared__ float pin[1024];
  float acc[16], a0[16];
  #pragma unroll
  for (int r = 0; r < 16; ++r) { acc[r] = 0.f; a0[r] = initA[(long)h * 16 + r]; }
  for (int n = 0; n < 32; ++n) {
    const int chunk = b * 32 + n;
    __syncthreads();
    #pragma unroll
    for (int i = 0; i < 4; ++i)
      pin[i * 256 + threadIdx.x] = projin[(long)chunk * 1024 + i * 256 + threadIdx.x];
    __syncthreads();
    bf16x8 w0, w1;
    #pragma unroll
    for (int r = 0; r < 8; ++r) {
      w0[r] = f2b(a0[r] - 0.02f * acc[r]);
      w1[r] = f2b(a0[r + 8] - 0.02f * acc[r + 8]);
    }
    short* dst = Aeff + ((long)chunk * 4096 + h) * 16;
    *(bf16x8*)dst = w0;
    *(bf16x8*)(dst + 8) = w1;
    for (int c = 0; c < 64; ++c) {
      const float v = b2f(V[((long)(chunk * 64 + c)) * 4096 + h]);
      #pragma unroll
      for (int r = 0; r < 16; ++r) acc[r] = fmaf(v, pin[c * 16 + r], acc[r]);
    }
  }
}

// ---------------- fused dB + exclusive cumsum -> B_eff (bf16) ----------------
__global__ __launch_bounds__(256) void beff_kernel(const short* __restrict__ X,
    const float* __restrict__ projerr, const float* __restrict__ initB,
    short* __restrict__ Beff) {
  const int b = blockIdx.y;
  const int k = blockIdx.x * 256 + threadIdx.x;  // 43*256 == 11008 exactly
  __shared__ float pe[1024];
  float acc[16], b0[16];
  #pragma unroll
  for (int r = 0; r < 16; ++r) { acc[r] = 0.f; b0[r] = initB[(long)r * 11008 + k]; }
  for (int n = 0; n < 32; ++n) {
    const int chunk = b * 32 + n;
    __syncthreads();
    #pragma unroll
    for (int i = 0; i < 4; ++i)
      pe[i * 256 + threadIdx.x] = projerr[(long)chunk * 1024 + i * 256 + threadIdx.x];
    __syncthreads();
    #pragma unroll
    for (int r = 0; r < 16; ++r)
      Beff[((long)chunk * 16 + r) * 11008 + k] = f2b(b0[r] - 0.02f * acc[r]);
    for (int c = 0; c < 64; ++c) {
      const float xv = b2f(X[((long)(chunk * 64 + c)) * 11008 + k]);
      #pragma unroll
      for (int r = 0; r < 16; ++r) acc[r] = fmaf(xv, pe[c * 16 + r], acc[r]);
    }
  }
}

// ---------------- out(f32) = base + 2 * mid @ A_eff^T ----------------
__global__ __launch_bounds__(256) void final_kernel(const float* __restrict__ base,
    const float* __restrict__ mid, const short* __restrict__ Aeff,
    float* __restrict__ out) {
  const int token = blockIdx.x;
  const int chunk = token >> 6;
  __shared__ float m[16];
  if (threadIdx.x < 16) m[threadIdx.x] = mid[(long)token * 16 + threadIdx.x];
  __syncthreads();
  float mf[16];
  #pragma unroll
  for (int r = 0; r < 16; ++r) mf[r] = m[r];
  for (int it = 0; it < 16; ++it) {
    const int h = it * 256 + threadIdx.x;
    const short* ar = Aeff + ((long)chunk * 4096 + h) * 16;
    bf16x8 a0 = *(const bf16x8*)ar;
    bf16x8 a1 = *(const bf16x8*)(ar + 8);
    float s = 0.f;
    #pragma unroll
    for (int j = 0; j < 8; ++j) {
      s = fmaf(mf[j], b2f(a0[j]), s);
      s = fmaf(mf[j + 8], b2f(a1[j]), s);
    }
    out[(long)token * 4096 + h] = base[(long)token * 4096 + h] + 2.0f * s;
  }
}

extern "C" void kernel_launch(void* const* d_in, const int* in_sizes, int n_in,
                              void* d_out, int out_size, void* d_ws, size_t ws_size,
                              hipStream_t stream) {
  const float* x     = (const float*)d_in[0];   // [2,2048,11008]
  const float* Wbase = (const float*)d_in[1];   // [4096,11008]
  const float* emb   = (const float*)d_in[2];   // [32000,4096]
  const float* Wproj = (const float*)d_in[3];   // [4096,4096]
  const float* initA = (const float*)d_in[4];   // [4096,16]
  const float* initB = (const float*)d_in[5];   // [16,11008]
  const int*   ids   = (const int*)d_in[6];     // [2,2048]
  float* outp = (float*)d_out;                  // f32 [2,2048,4096]

  char* p = (char*)d_ws;
  short* xb   = (short*)p; p += 90177536L;   // x bf16
  short* Wb   = (short*)p; p += 90177536L;   // W_base bf16
  short* Wpb  = (short*)p; p += 33554432L;   // W_proj bf16
  short* shb  = (short*)p; p += 33554432L;   // shifted embeds bf16
  short* Vb   = (short*)p; p += 33554432L;   // V bf16
  float* base = (float*)p; p += 67108864L;   // base_out f32
  short* iBb  = (short*)p; p += 352256L;     // init_B bf16
  short* iAt  = (short*)p; p += 131072L;     // init_A^T bf16 [16][4096]
  float* pin  = (float*)p; p += 262144L;     // proj_in f32 [4096][16]
  float* per  = (float*)p; p += 262144L;     // proj_err f32 [4096][16]
  float* mid  = (float*)p; p += 262144L;     // mid f32 [4096][16]
  short* Aeff = (short*)p; p += 8388608L;    // [64][4096][16] bf16
  short* Beff = (short*)p; p += 22544384L;   // [64][16][11008] bf16

  cvt_kernel<<<2048, 256, 0, stream>>>(x, xb, 45088768L);
  cvt_kernel<<<2048, 256, 0, stream>>>(Wbase, Wb, 45088768L);
  cvt_kernel<<<2048, 256, 0, stream>>>(Wproj, Wpb, 16777216L);
  cvt_kernel<<<86, 256, 0, stream>>>(initB, iBb, 176128L);
  tposeA_kernel<<<16, 256, 0, stream>>>(initA, iAt);
  gather_kernel<<<4096, 256, 0, stream>>>(emb, ids, shb);

  gemm8p<1><<<256, 512, 0, stream>>>(shb, Wpb, (void*)Vb, 4096, 4096, 4096);
  gemm8p<0><<<256, 512, 0, stream>>>(xb, Wb, (void*)base, 4096, 4096, 11008);

  rowgemm16<<<1024, 256, 0, stream>>>(xb, iBb, pin, 11008, 0L);   // proj_in
  rowgemm16<<<1024, 256, 0, stream>>>(Vb, iAt, per, 4096, 0L);    // proj_err

  aeff_kernel<<<dim3(16, 2), 256, 0, stream>>>(Vb, pin, initA, Aeff);
  beff_kernel<<<dim3(43, 2), 256, 0, stream>>>(xb, per, initB, Beff);

  rowgemm16<<<1024, 256, 0, stream>>>(xb, Beff, mid, 11008, 176128L);  // mid
  final_kernel<<<4096, 256, 0, stream>>>(base, mid, Aeff, outp);
}

// Round 4
// 1097.109 us; speedup vs baseline: 2.1913x; 1.6393x over previous
//
#include <hip/hip_runtime.h>

typedef __attribute__((ext_vector_type(8))) short bf16x8;
typedef __attribute__((ext_vector_type(4))) float f32x4;

__device__ __forceinline__ float b2f(short s) {
  return __uint_as_float(((unsigned int)(unsigned short)s) << 16);
}
__device__ __forceinline__ short f2b(float f) {
  unsigned int u = __float_as_uint(f);
  unsigned int r = (u + 0x7fffu + ((u >> 16) & 1u)) >> 16;
  return (short)(unsigned short)r;
}

#define GLOAD16(g, l) __builtin_amdgcn_global_load_lds( \
    (const __attribute__((address_space(1))) void*)(g),  \
    (__attribute__((address_space(3))) void*)(l), 16, 0, 0)

// ---------------- f32 -> bf16 convert ----------------
__global__ __launch_bounds__(256) void cvt_kernel(const float* __restrict__ src,
                                                  short* __restrict__ dst, long n) {
  long i = ((long)blockIdx.x * 256 + threadIdx.x) * 8;
  long stride = (long)gridDim.x * 256 * 8;
  for (; i + 8 <= n; i += stride) {
    float4 a = *(const float4*)(src + i);
    float4 b = *(const float4*)(src + i + 4);
    bf16x8 o;
    o[0] = f2b(a.x); o[1] = f2b(a.y); o[2] = f2b(a.z); o[3] = f2b(a.w);
    o[4] = f2b(b.x); o[5] = f2b(b.y); o[6] = f2b(b.z); o[7] = f2b(b.w);
    *(bf16x8*)(dst + i) = o;
  }
}

// ---------------- gather next-token embeddings, shift, convert ----------------
__global__ __launch_bounds__(256) void gather_kernel(const float* __restrict__ emb,
    const int* __restrict__ ids, short* __restrict__ sh) {
  const int token = blockIdx.x;          // 0..4095, token = b*2048 + s
  const int s = token & 2047;
  const long dst = (long)token * 4096;
  const int row = (s == 2047) ? -1 : ids[token + 1];
  for (int it = 0; it < 2; ++it) {
    const int e = it * 2048 + threadIdx.x * 8;
    bf16x8 o;
    if (row < 0) {
      #pragma unroll
      for (int j = 0; j < 8; ++j) o[j] = 0;
    } else {
      float4 a = *(const float4*)(emb + (long)row * 4096 + e);
      float4 b = *(const float4*)(emb + (long)row * 4096 + e + 4);
      o[0] = f2b(a.x); o[1] = f2b(a.y); o[2] = f2b(a.z); o[3] = f2b(a.w);
      o[4] = f2b(b.x); o[5] = f2b(b.y); o[6] = f2b(b.z); o[7] = f2b(b.w);
    }
    *(bf16x8*)(sh + dst + e) = o;
  }
}

// ---------------- init_A [4096][16] f32 -> [16][4096] bf16 ----------------
__global__ __launch_bounds__(256) void tposeA_kernel(const float* __restrict__ A,
                                                     short* __restrict__ At) {
  const int h = blockIdx.x * 256 + threadIdx.x;
  #pragma unroll
  for (int r = 0; r < 16; ++r) At[(long)r * 4096 + h] = f2b(A[(long)h * 16 + r]);
}

// ======== deep-pipelined 256x256 MFMA GEMM: C[M,N] = A[M,K] @ B[N,K]^T ========
// BK=64, 8 waves (2M x 4N, each 128x64 out), double-buffered LDS (128 KiB).
// Coalesced staging: each wave stages 8 rows x 128B contiguous per chunk; the
// 16B k-chunk of row rho lands at slot (kc ^ rho) within the row-group (XOR
// swizzle applied via per-lane GLOBAL source address; LDS dest lane-linear).
// Granule layout (16B units): G(R, kc) = (R>>3)*64 + (R&7)*8 + (kc ^ (R&7)).
// Single vmcnt(6) per K-tile at phase 3; raw barriers; lgkmcnt(0)+sched_barrier
// before each 16-MFMA cluster; setprio around MFMA; XCD-bijective swizzle.
template <int OUTBF16>
__global__ __launch_bounds__(512, 2) void gemm8p(const short* __restrict__ A,
    const short* __restrict__ B, void* __restrict__ C, int M, int N, int Kd) {
  __shared__ short lds[65536];  // 128 KiB: buf{0,1} x [A 32K | B 32K]
  const int tid = threadIdx.x;
  const int lane = tid & 63;
  const int wid = tid >> 6;        // 0..7
  const int wr = wid >> 2;         // 0..1  (M half)
  const int wcn = wid & 3;         // 0..3  (N quarter)
  const int l15 = lane & 15, l4 = lane >> 4, l7 = lane & 7;
  const int lb = (lane >> 3) & 1;

  // XCD-aware bijective swizzle (grid = 256, multiple of 8)
  const int nbx = N >> 8;
  const int cpx = gridDim.x >> 3;
  const int wg = ((int)blockIdx.x & 7) * cpx + ((int)blockIdx.x >> 3);
  const long m0 = (long)(wg / nbx) * 256;
  const long n0 = (long)(wg % nbx) * 256;

  const int NT = Kd >> 6;

  // staging source: wave stages rows g*8..g*8+7 (g = c*8+wid), lane's row rho =
  // lane>>3, k-slot j = lane&7 holds kc = j ^ rho.
  const int rho = lane >> 3;
  const short* Ag = A + (m0 + wid * 8 + rho) * (long)Kd + (l7 ^ rho) * 8;
  const short* Bg = B + (n0 + wid * 8 + rho) * (long)Kd + (l7 ^ rho) * 8;

#define STAGE_A(b, kt, c) GLOAD16(Ag + (long)(c) * 64 * Kd + (long)(kt) * 64, \
    (char*)lds + (b) * 65536 + ((c) * 8 + wid) * 1024 + lane * 16)
#define STAGE_B(b, kt, c) GLOAD16(Bg + (long)(c) * 64 * Kd + (long)(kt) * 64, \
    (char*)lds + (b) * 65536 + 32768 + ((c) * 8 + wid) * 1024 + lane * 16)

  // fragment read lane offsets (bytes): G = lb*64 + l7*8 + ((h*4+l4) ^ l7)
  int aLane[2], bLane[2];
  #pragma unroll
  for (int h = 0; h < 2; ++h) {
    aLane[h] = (lb * 64 + l7 * 8 + ((h * 4 + l4) ^ l7)) * 16;
    bLane[h] = aLane[h] + 32768;
  }

  f32x4 acc[8][4];
  #pragma unroll
  for (int m = 0; m < 8; ++m)
    #pragma unroll
    for (int n = 0; n < 4; ++n) {
      acc[m][n][0] = 0.f; acc[m][n][1] = 0.f;
      acc[m][n][2] = 0.f; acc[m][n][3] = 0.f;
    }

  // -------- prologue: tile 0 complete (8 chunks) + tile 1 chunks 0..2 --------
  STAGE_A(0, 0, 0); STAGE_B(0, 0, 0);
  STAGE_A(0, 0, 1); STAGE_B(0, 0, 1);
  STAGE_A(0, 0, 2); STAGE_B(0, 0, 2);
  STAGE_A(0, 0, 3); STAGE_B(0, 0, 3);
  STAGE_A(1, 1, 0); STAGE_B(1, 1, 0);
  STAGE_A(1, 1, 1); STAGE_B(1, 1, 1);
  STAGE_A(1, 1, 2); STAGE_B(1, 1, 2);
  asm volatile("s_waitcnt vmcnt(6)" ::: "memory");
  __builtin_amdgcn_s_barrier();
  asm volatile("" ::: "memory");

  for (int t = 0; t < NT; ++t) {
    const int cur = t & 1;
    const int tn1 = (t + 1 < NT) ? t + 1 : 0;   // wrap -> garbage stage, safe slot
    const int tn2 = (t + 2 < NT) ? t + 2 : 0;
    const char* pbuf = (const char*)lds + cur * 65536;
    bf16x8 bv[4][2];
    #pragma unroll
    for (int q = 0; q < 4; ++q) {
      bf16x8 av[2][2];
      if (q == 0) {
        #pragma unroll
        for (int nf = 0; nf < 4; ++nf) {
          bv[nf][0] = *(const bf16x8*)(pbuf + wcn * 8192 + nf * 2048 + bLane[0]);
          bv[nf][1] = *(const bf16x8*)(pbuf + wcn * 8192 + nf * 2048 + bLane[1]);
        }
      }
      #pragma unroll
      for (int sub = 0; sub < 2; ++sub) {
        av[sub][0] = *(const bf16x8*)(pbuf + q * 8192 + wr * 4096 + sub * 2048 + aLane[0]);
        av[sub][1] = *(const bf16x8*)(pbuf + q * 8192 + wr * 4096 + sub * 2048 + aLane[1]);
      }
      // --- stage 2 chunks (prefetch ~1.75 tiles ahead) ---
      if (q == 0) { STAGE_A(cur ^ 1, tn1, 3); STAGE_B(cur ^ 1, tn1, 3); }
      else        { STAGE_A(cur, tn2, q - 1); STAGE_B(cur, tn2, q - 1); }
      // --- tile-boundary wait: validate tile t+1 before its phase-0 reads ---
      if (q == 3) asm volatile("s_waitcnt vmcnt(6)" ::: "memory");
      __builtin_amdgcn_s_barrier();
      asm volatile("s_waitcnt lgkmcnt(0)" ::: "memory");
      __builtin_amdgcn_sched_barrier(0);
      __builtin_amdgcn_s_setprio(1);
      #pragma unroll
      for (int sub = 0; sub < 2; ++sub)
        #pragma unroll
        for (int nf = 0; nf < 4; ++nf) {
          acc[q * 2 + sub][nf] = __builtin_amdgcn_mfma_f32_16x16x32_bf16(
              av[sub][0], bv[nf][0], acc[q * 2 + sub][nf], 0, 0, 0);
          acc[q * 2 + sub][nf] = __builtin_amdgcn_mfma_f32_16x16x32_bf16(
              av[sub][1], bv[nf][1], acc[q * 2 + sub][nf], 0, 0, 0);
        }
      __builtin_amdgcn_s_setprio(0);
      __builtin_amdgcn_s_barrier();
      asm volatile("" ::: "memory");
    }
  }
#undef STAGE_A
#undef STAGE_B

  // -------- epilogue: C write --------
  #pragma unroll
  for (int q = 0; q < 4; ++q)
    #pragma unroll
    for (int sub = 0; sub < 2; ++sub)
      #pragma unroll
      for (int nf = 0; nf < 4; ++nf)
        #pragma unroll
        for (int j = 0; j < 4; ++j) {
          const long row = m0 + q * 64 + wr * 32 + sub * 16 + l4 * 4 + j;
          const long col = n0 + wcn * 64 + nf * 16 + l15;
          if (OUTBF16) ((short*)C)[row * N + col] = f2b(acc[q * 2 + sub][nf][j]);
          else         ((float*)C)[row * N + col] = acc[q * 2 + sub][nf][j];
        }
}

// ---------------- skinny GEMM: out[t][16] = X[t,:] @ W[16,K]^T ----------------
__global__ __launch_bounds__(256) void rowgemm16(const short* __restrict__ X,
    const short* __restrict__ W, float* __restrict__ out, int K, long wStride) {
  const int lane = threadIdx.x & 63;
  const int token = blockIdx.x * 4 + (threadIdx.x >> 6);
  const short* Xr = X + (long)token * K;
  const short* Wr = W + (long)(token >> 6) * wStride;
  float acc[16];
  #pragma unroll
  for (int r = 0; r < 16; ++r) acc[r] = 0.f;
  const int nIter = (K + 511) >> 9;
  for (int i = 0; i < nIter; ++i) {
    const int k = i * 512 + lane * 8;
    if (k + 8 <= K) {
      bf16x8 xv = *(const bf16x8*)(Xr + k);
      float xf[8];
      #pragma unroll
      for (int j = 0; j < 8; ++j) xf[j] = b2f(xv[j]);
      #pragma unroll
      for (int r = 0; r < 16; ++r) {
        bf16x8 wv = *(const bf16x8*)(Wr + (long)r * K + k);
        #pragma unroll
        for (int j = 0; j < 8; ++j) acc[r] = fmaf(xf[j], b2f(wv[j]), acc[r]);
      }
    }
  }
  #pragma unroll
  for (int r = 0; r < 16; ++r) {
    float v = acc[r];
    #pragma unroll
    for (int off = 32; off > 0; off >>= 1) v += __shfl_xor(v, off, 64);
    acc[r] = v;
  }
  if (lane == 0) {
    #pragma unroll
    for (int r = 0; r < 16; ++r) out[(long)token * 16 + r] = acc[r];
  }
}

// ---------------- fused dA + exclusive cumsum -> A_eff (bf16) ----------------
// 4-way rank split: block handles ranks rg*4..rg*4+3 for 256 h's.
__global__ __launch_bounds__(256) void aeff_kernel(const short* __restrict__ V,
    const float* __restrict__ projin, const float* __restrict__ initA,
    short* __restrict__ Aeff) {
  const int b = blockIdx.y, rg = blockIdx.z;
  const int h = blockIdx.x * 256 + threadIdx.x;
  __shared__ float pes[256];
  float acc[4], a0[4];
  #pragma unroll
  for (int r = 0; r < 4; ++r) {
    acc[r] = 0.f;
    a0[r] = initA[(long)h * 16 + rg * 4 + r];
  }
  for (int n = 0; n < 32; ++n) {
    const int chunk = b * 32 + n;
    __syncthreads();
    pes[threadIdx.x] = projin[(long)chunk * 1024 + (threadIdx.x >> 2) * 16 +
                              rg * 4 + (threadIdx.x & 3)];
    __syncthreads();
    short4 w;
    w.x = f2b(a0[0] - 0.02f * acc[0]);
    w.y = f2b(a0[1] - 0.02f * acc[1]);
    w.z = f2b(a0[2] - 0.02f * acc[2]);
    w.w = f2b(a0[3] - 0.02f * acc[3]);
    *(short4*)(Aeff + ((long)chunk * 4096 + h) * 16 + rg * 4) = w;
    for (int c = 0; c < 64; ++c) {
      const float v = b2f(V[((long)(chunk * 64 + c)) * 4096 + h]);
      f32x4 pv = *(const f32x4*)(pes + c * 4);
      #pragma unroll
      for (int r = 0; r < 4; ++r) acc[r] = fmaf(v, pv[r], acc[r]);
    }
  }
}

// ---------------- fused dB + exclusive cumsum -> B_eff (bf16) ----------------
__global__ __launch_bounds__(256) void beff_kernel(const short* __restrict__ X,
    const float* __restrict__ projerr, const float* __restrict__ initB,
    short* __restrict__ Beff) {
  const int b = blockIdx.y, rg = blockIdx.z;
  const int k = blockIdx.x * 256 + threadIdx.x;  // 43*256 == 11008
  __shared__ float pes[256];
  float acc[4], b0[4];
  #pragma unroll
  for (int r = 0; r < 4; ++r) {
    acc[r] = 0.f;
    b0[r] = initB[(long)(rg * 4 + r) * 11008 + k];
  }
  for (int n = 0; n < 32; ++n) {
    const int chunk = b * 32 + n;
    __syncthreads();
    pes[threadIdx.x] = projerr[(long)chunk * 1024 + (threadIdx.x >> 2) * 16 +
                               rg * 4 + (threadIdx.x & 3)];
    __syncthreads();
    #pragma unroll
    for (int r = 0; r < 4; ++r)
      Beff[((long)chunk * 16 + rg * 4 + r) * 11008 + k] = f2b(b0[r] - 0.02f * acc[r]);
    for (int c = 0; c < 64; ++c) {
      const float xv = b2f(X[((long)(chunk * 64 + c)) * 11008 + k]);
      f32x4 pv = *(const f32x4*)(pes + c * 4);
      #pragma unroll
      for (int r = 0; r < 4; ++r) acc[r] = fmaf(xv, pv[r], acc[r]);
    }
  }
}

// ---------------- out(f32) = base + 2 * mid @ A_eff^T ----------------
__global__ __launch_bounds__(256) void final_kernel(const float* __restrict__ base,
    const float* __restrict__ mid, const short* __restrict__ Aeff,
    float* __restrict__ out) {
  const int token = blockIdx.x;
  const int chunk = token >> 6;
  __shared__ float m[16];
  if (threadIdx.x < 16) m[threadIdx.x] = mid[(long)token * 16 + threadIdx.x];
  __syncthreads();
  float mf[16];
  #pragma unroll
  for (int r = 0; r < 16; ++r) mf[r] = m[r];
  for (int it = 0; it < 16; ++it) {
    const int h = it * 256 + threadIdx.x;
    const short* ar = Aeff + ((long)chunk * 4096 + h) * 16;
    bf16x8 a0 = *(const bf16x8*)ar;
    bf16x8 a1 = *(const bf16x8*)(ar + 8);
    float s = 0.f;
    #pragma unroll
    for (int j = 0; j < 8; ++j) {
      s = fmaf(mf[j], b2f(a0[j]), s);
      s = fmaf(mf[j + 8], b2f(a1[j]), s);
    }
    out[(long)token * 4096 + h] = base[(long)token * 4096 + h] + 2.0f * s;
  }
}

extern "C" void kernel_launch(void* const* d_in, const int* in_sizes, int n_in,
                              void* d_out, int out_size, void* d_ws, size_t ws_size,
                              hipStream_t stream) {
  const float* x     = (const float*)d_in[0];   // [2,2048,11008]
  const float* Wbase = (const float*)d_in[1];   // [4096,11008]
  const float* emb   = (const float*)d_in[2];   // [32000,4096]
  const float* Wproj = (const float*)d_in[3];   // [4096,4096]
  const float* initA = (const float*)d_in[4];   // [4096,16]
  const float* initB = (const float*)d_in[5];   // [16,11008]
  const int*   ids   = (const int*)d_in[6];     // [2,2048]
  float* outp = (float*)d_out;                  // f32 [2,2048,4096]

  char* p = (char*)d_ws;
  short* xb   = (short*)p; p += 90177536L;   // x bf16
  short* Wb   = (short*)p; p += 90177536L;   // W_base bf16
  short* Wpb  = (short*)p; p += 33554432L;   // W_proj bf16
  short* shb  = (short*)p; p += 33554432L;   // shifted embeds bf16
  short* Vb   = (short*)p; p += 33554432L;   // V bf16
  float* base = (float*)p; p += 67108864L;   // base_out f32
  short* iBb  = (short*)p; p += 352256L;     // init_B bf16
  short* iAt  = (short*)p; p += 131072L;     // init_A^T bf16 [16][4096]
  float* pin  = (float*)p; p += 262144L;     // proj_in f32 [4096][16]
  float* per  = (float*)p; p += 262144L;     // proj_err f32 [4096][16]
  float* mid  = (float*)p; p += 262144L;     // mid f32 [4096][16]
  short* Aeff = (short*)p; p += 8388608L;    // [64][4096][16] bf16
  short* Beff = (short*)p; p += 22544384L;   // [64][16][11008] bf16

  cvt_kernel<<<2048, 256, 0, stream>>>(x, xb, 45088768L);
  cvt_kernel<<<2048, 256, 0, stream>>>(Wbase, Wb, 45088768L);
  cvt_kernel<<<2048, 256, 0, stream>>>(Wproj, Wpb, 16777216L);
  cvt_kernel<<<86, 256, 0, stream>>>(initB, iBb, 176128L);
  tposeA_kernel<<<16, 256, 0, stream>>>(initA, iAt);
  gather_kernel<<<4096, 256, 0, stream>>>(emb, ids, shb);

  gemm8p<1><<<256, 512, 0, stream>>>(shb, Wpb, (void*)Vb, 4096, 4096, 4096);
  gemm8p<0><<<256, 512, 0, stream>>>(xb, Wb, (void*)base, 4096, 4096, 11008);

  rowgemm16<<<1024, 256, 0, stream>>>(xb, iBb, pin, 11008, 0L);   // proj_in
  rowgemm16<<<1024, 256, 0, stream>>>(Vb, iAt, per, 4096, 0L);    // proj_err

  aeff_kernel<<<dim3(16, 2, 4), 256, 0, stream>>>(Vb, pin, initA, Aeff);
  beff_kernel<<<dim3(43, 2, 4), 256, 0, stream>>>(xb, per, initB, Beff);

  rowgemm16<<<1024, 256, 0, stream>>>(xb, Beff, mid, 11008, 176128L);  // mid
  final_kernel<<<4096, 256, 0, stream>>>(base, mid, Aeff, outp);
}

// Round 5
// 899.548 us; speedup vs baseline: 2.6725x; 1.2196x over previous
//
#include <hip/hip_runtime.h>

typedef __attribute__((ext_vector_type(8))) short bf16x8;
typedef __attribute__((ext_vector_type(4))) float f32x4;

__device__ __forceinline__ float b2f(short s) {
  return __uint_as_float(((unsigned int)(unsigned short)s) << 16);
}
__device__ __forceinline__ short f2b(float f) {
  unsigned int u = __float_as_uint(f);
  unsigned int r = (u + 0x7fffu + ((u >> 16) & 1u)) >> 16;
  return (short)(unsigned short)r;
}

#define GLOAD16(g, l) __builtin_amdgcn_global_load_lds( \
    (const __attribute__((address_space(1))) void*)(g),  \
    (__attribute__((address_space(3))) void*)(l), 16, 0, 0)

// ---------------- f32 -> bf16 convert ----------------
__global__ __launch_bounds__(256) void cvt_kernel(const float* __restrict__ src,
                                                  short* __restrict__ dst, long n) {
  long i = ((long)blockIdx.x * 256 + threadIdx.x) * 8;
  long stride = (long)gridDim.x * 256 * 8;
  for (; i + 8 <= n; i += stride) {
    float4 a = *(const float4*)(src + i);
    float4 b = *(const float4*)(src + i + 4);
    bf16x8 o;
    o[0] = f2b(a.x); o[1] = f2b(a.y); o[2] = f2b(a.z); o[3] = f2b(a.w);
    o[4] = f2b(b.x); o[5] = f2b(b.y); o[6] = f2b(b.z); o[7] = f2b(b.w);
    *(bf16x8*)(dst + i) = o;
  }
}

// ---------------- gather next-token embeddings, shift, convert ----------------
__global__ __launch_bounds__(256) void gather_kernel(const float* __restrict__ emb,
    const int* __restrict__ ids, short* __restrict__ sh) {
  const int token = blockIdx.x;          // 0..4095, token = b*2048 + s
  const int s = token & 2047;
  const long dst = (long)token * 4096;
  const int row = (s == 2047) ? -1 : ids[token + 1];
  for (int it = 0; it < 2; ++it) {
    const int e = it * 2048 + threadIdx.x * 8;
    bf16x8 o;
    if (row < 0) {
      #pragma unroll
      for (int j = 0; j < 8; ++j) o[j] = 0;
    } else {
      float4 a = *(const float4*)(emb + (long)row * 4096 + e);
      float4 b = *(const float4*)(emb + (long)row * 4096 + e + 4);
      o[0] = f2b(a.x); o[1] = f2b(a.y); o[2] = f2b(a.z); o[3] = f2b(a.w);
      o[4] = f2b(b.x); o[5] = f2b(b.y); o[6] = f2b(b.z); o[7] = f2b(b.w);
    }
    *(bf16x8*)(sh + dst + e) = o;
  }
}

// ---------------- init_A [4096][16] f32 -> [16][4096] bf16 ----------------
__global__ __launch_bounds__(256) void tposeA_kernel(const float* __restrict__ A,
                                                     short* __restrict__ At) {
  const int h = blockIdx.x * 256 + threadIdx.x;
  #pragma unroll
  for (int r = 0; r < 16; ++r) At[(long)r * 4096 + h] = f2b(A[(long)h * 16 + r]);
}

// ======== deep-pipelined 256x256 MFMA GEMM: C[M,N] = A[M,K] @ B[N,K]^T ========
// (unchanged from round 4 — see comments there)
template <int OUTBF16>
__global__ __launch_bounds__(512, 2) void gemm8p(const short* __restrict__ A,
    const short* __restrict__ B, void* __restrict__ C, int M, int N, int Kd) {
  __shared__ short lds[65536];  // 128 KiB: buf{0,1} x [A 32K | B 32K]
  const int tid = threadIdx.x;
  const int lane = tid & 63;
  const int wid = tid >> 6;        // 0..7
  const int wr = wid >> 2;         // 0..1  (M half)
  const int wcn = wid & 3;         // 0..3  (N quarter)
  const int l15 = lane & 15, l4 = lane >> 4, l7 = lane & 7;
  const int lb = (lane >> 3) & 1;

  const int nbx = N >> 8;
  const int cpx = gridDim.x >> 3;
  const int wg = ((int)blockIdx.x & 7) * cpx + ((int)blockIdx.x >> 3);
  const long m0 = (long)(wg / nbx) * 256;
  const long n0 = (long)(wg % nbx) * 256;

  const int NT = Kd >> 6;

  const int rho = lane >> 3;
  const short* Ag = A + (m0 + wid * 8 + rho) * (long)Kd + (l7 ^ rho) * 8;
  const short* Bg = B + (n0 + wid * 8 + rho) * (long)Kd + (l7 ^ rho) * 8;

#define STAGE_A(b, kt, c) GLOAD16(Ag + (long)(c) * 64 * Kd + (long)(kt) * 64, \
    (char*)lds + (b) * 65536 + ((c) * 8 + wid) * 1024 + lane * 16)
#define STAGE_B(b, kt, c) GLOAD16(Bg + (long)(c) * 64 * Kd + (long)(kt) * 64, \
    (char*)lds + (b) * 65536 + 32768 + ((c) * 8 + wid) * 1024 + lane * 16)

  int aLane[2], bLane[2];
  #pragma unroll
  for (int h = 0; h < 2; ++h) {
    aLane[h] = (lb * 64 + l7 * 8 + ((h * 4 + l4) ^ l7)) * 16;
    bLane[h] = aLane[h] + 32768;
  }

  f32x4 acc[8][4];
  #pragma unroll
  for (int m = 0; m < 8; ++m)
    #pragma unroll
    for (int n = 0; n < 4; ++n) {
      acc[m][n][0] = 0.f; acc[m][n][1] = 0.f;
      acc[m][n][2] = 0.f; acc[m][n][3] = 0.f;
    }

  STAGE_A(0, 0, 0); STAGE_B(0, 0, 0);
  STAGE_A(0, 0, 1); STAGE_B(0, 0, 1);
  STAGE_A(0, 0, 2); STAGE_B(0, 0, 2);
  STAGE_A(0, 0, 3); STAGE_B(0, 0, 3);
  STAGE_A(1, 1, 0); STAGE_B(1, 1, 0);
  STAGE_A(1, 1, 1); STAGE_B(1, 1, 1);
  STAGE_A(1, 1, 2); STAGE_B(1, 1, 2);
  asm volatile("s_waitcnt vmcnt(6)" ::: "memory");
  __builtin_amdgcn_s_barrier();
  asm volatile("" ::: "memory");

  for (int t = 0; t < NT; ++t) {
    const int cur = t & 1;
    const int tn1 = (t + 1 < NT) ? t + 1 : 0;
    const int tn2 = (t + 2 < NT) ? t + 2 : 0;
    const char* pbuf = (const char*)lds + cur * 65536;
    bf16x8 bv[4][2];
    #pragma unroll
    for (int q = 0; q < 4; ++q) {
      bf16x8 av[2][2];
      if (q == 0) {
        #pragma unroll
        for (int nf = 0; nf < 4; ++nf) {
          bv[nf][0] = *(const bf16x8*)(pbuf + wcn * 8192 + nf * 2048 + bLane[0]);
          bv[nf][1] = *(const bf16x8*)(pbuf + wcn * 8192 + nf * 2048 + bLane[1]);
        }
      }
      #pragma unroll
      for (int sub = 0; sub < 2; ++sub) {
        av[sub][0] = *(const bf16x8*)(pbuf + q * 8192 + wr * 4096 + sub * 2048 + aLane[0]);
        av[sub][1] = *(const bf16x8*)(pbuf + q * 8192 + wr * 4096 + sub * 2048 + aLane[1]);
      }
      if (q == 0) { STAGE_A(cur ^ 1, tn1, 3); STAGE_B(cur ^ 1, tn1, 3); }
      else        { STAGE_A(cur, tn2, q - 1); STAGE_B(cur, tn2, q - 1); }
      if (q == 3) asm volatile("s_waitcnt vmcnt(6)" ::: "memory");
      __builtin_amdgcn_s_barrier();
      asm volatile("s_waitcnt lgkmcnt(0)" ::: "memory");
      __builtin_amdgcn_sched_barrier(0);
      __builtin_amdgcn_s_setprio(1);
      #pragma unroll
      for (int sub = 0; sub < 2; ++sub)
        #pragma unroll
        for (int nf = 0; nf < 4; ++nf) {
          acc[q * 2 + sub][nf] = __builtin_amdgcn_mfma_f32_16x16x32_bf16(
              av[sub][0], bv[nf][0], acc[q * 2 + sub][nf], 0, 0, 0);
          acc[q * 2 + sub][nf] = __builtin_amdgcn_mfma_f32_16x16x32_bf16(
              av[sub][1], bv[nf][1], acc[q * 2 + sub][nf], 0, 0, 0);
        }
      __builtin_amdgcn_s_setprio(0);
      __builtin_amdgcn_s_barrier();
      asm volatile("" ::: "memory");
    }
  }
#undef STAGE_A
#undef STAGE_B

  #pragma unroll
  for (int q = 0; q < 4; ++q)
    #pragma unroll
    for (int sub = 0; sub < 2; ++sub)
      #pragma unroll
      for (int nf = 0; nf < 4; ++nf)
        #pragma unroll
        for (int j = 0; j < 4; ++j) {
          const long row = m0 + q * 64 + wr * 32 + sub * 16 + l4 * 4 + j;
          const long col = n0 + wcn * 64 + nf * 16 + l15;
          if (OUTBF16) ((short*)C)[row * N + col] = f2b(acc[q * 2 + sub][nf][j]);
          else         ((float*)C)[row * N + col] = acc[q * 2 + sub][nf][j];
        }
}

// ---------------- skinny GEMM: out[t][16] = X[t,:] @ W[16,K]^T ----------------
__global__ __launch_bounds__(256) void rowgemm16(const short* __restrict__ X,
    const short* __restrict__ W, float* __restrict__ out, int K, long wStride) {
  const int lane = threadIdx.x & 63;
  const int token = blockIdx.x * 4 + (threadIdx.x >> 6);
  const short* Xr = X + (long)token * K;
  const short* Wr = W + (long)(token >> 6) * wStride;
  float acc[16];
  #pragma unroll
  for (int r = 0; r < 16; ++r) acc[r] = 0.f;
  const int nIter = (K + 511) >> 9;
  for (int i = 0; i < nIter; ++i) {
    const int k = i * 512 + lane * 8;
    if (k + 8 <= K) {
      bf16x8 xv = *(const bf16x8*)(Xr + k);
      float xf[8];
      #pragma unroll
      for (int j = 0; j < 8; ++j) xf[j] = b2f(xv[j]);
      #pragma unroll
      for (int r = 0; r < 16; ++r) {
        bf16x8 wv = *(const bf16x8*)(Wr + (long)r * K + k);
        #pragma unroll
        for (int j = 0; j < 8; ++j) acc[r] = fmaf(xf[j], b2f(wv[j]), acc[r]);
      }
    }
  }
  #pragma unroll
  for (int r = 0; r < 16; ++r) {
    float v = acc[r];
    #pragma unroll
    for (int off = 32; off > 0; off >>= 1) v += __shfl_xor(v, off, 64);
    acc[r] = v;
  }
  if (lane == 0) {
    #pragma unroll
    for (int r = 0; r < 16; ++r) out[(long)token * 16 + r] = acc[r];
  }
}

// ---------------- pass 1a: dA[chunk][h][r] = sum_c V[c,h]*pin[c,r] ----------------
__global__ __launch_bounds__(256) void dA_kernel(const short* __restrict__ V,
    const float* __restrict__ pin, float* __restrict__ dA) {
  const int chunk = blockIdx.y;
  const int h = blockIdx.x * 256 + threadIdx.x;
  __shared__ float ps[1024];
  #pragma unroll
  for (int i = 0; i < 4; ++i)
    ps[i * 256 + threadIdx.x] = pin[(long)chunk * 1024 + i * 256 + threadIdx.x];
  __syncthreads();
  float acc[16];
  #pragma unroll
  for (int r = 0; r < 16; ++r) acc[r] = 0.f;
  for (int c = 0; c < 64; ++c) {
    const float v = b2f(V[((long)chunk * 64 + c) * 4096 + h]);
    #pragma unroll
    for (int r = 0; r < 16; ++r) acc[r] = fmaf(v, ps[c * 16 + r], acc[r]);
  }
  float* dst = dA + ((long)chunk * 4096 + h) * 16;
  #pragma unroll
  for (int i = 0; i < 4; ++i) {
    f32x4 w; w[0] = acc[i*4]; w[1] = acc[i*4+1]; w[2] = acc[i*4+2]; w[3] = acc[i*4+3];
    *(f32x4*)(dst + i * 4) = w;
  }
}

// ---------------- pass 1b: dB[chunk][r][k] = sum_c per[c,r]*X[c,k] ----------------
__global__ __launch_bounds__(256) void dB_kernel(const short* __restrict__ X,
    const float* __restrict__ per, float* __restrict__ dB) {
  const int chunk = blockIdx.y;
  const int k = blockIdx.x * 256 + threadIdx.x;   // 43*256 == 11008
  __shared__ float ps[1024];
  #pragma unroll
  for (int i = 0; i < 4; ++i)
    ps[i * 256 + threadIdx.x] = per[(long)chunk * 1024 + i * 256 + threadIdx.x];
  __syncthreads();
  float acc[16];
  #pragma unroll
  for (int r = 0; r < 16; ++r) acc[r] = 0.f;
  for (int c = 0; c < 64; ++c) {
    const float xv = b2f(X[((long)chunk * 64 + c) * 11008 + k]);
    #pragma unroll
    for (int r = 0; r < 16; ++r) acc[r] = fmaf(xv, ps[c * 16 + r], acc[r]);
  }
  #pragma unroll
  for (int r = 0; r < 16; ++r)
    dB[((long)chunk * 16 + r) * 11008 + k] = acc[r];
}

// ---------- pass 2a: exclusive scan over chunks -> A_eff bf16 ----------
__global__ __launch_bounds__(256) void scanA_kernel(const float* __restrict__ dA,
    const float* __restrict__ initA, short* __restrict__ Aeff) {
  const int b = blockIdx.y;
  const long idx = (long)blockIdx.x * 256 + threadIdx.x;  // h*16+r, < 65536
  const float a0 = initA[idx];
  float acc = 0.f;
  for (int n = 0; n < 32; ++n) {
    const long chunk = (long)b * 32 + n;
    Aeff[chunk * 65536 + idx] = f2b(a0 - 0.02f * acc);
    acc += dA[chunk * 65536 + idx];
  }
}

// ---------- pass 2b: exclusive scan over chunks -> B_eff bf16 ----------
__global__ __launch_bounds__(256) void scanB_kernel(const float* __restrict__ dB,
    const float* __restrict__ initB, short* __restrict__ Beff) {
  const int b = blockIdx.y;
  const long idx = (long)blockIdx.x * 256 + threadIdx.x;  // r*11008+k, < 176128
  const float b0 = initB[idx];
  float acc = 0.f;
  for (int n = 0; n < 32; ++n) {
    const long chunk = (long)b * 32 + n;
    Beff[chunk * 176128 + idx] = f2b(b0 - 0.02f * acc);
    acc += dB[chunk * 176128 + idx];
  }
}

// ---------------- out(f32) = base(bf16) + 2 * mid @ A_eff^T ----------------
__global__ __launch_bounds__(256) void final_kernel(const short* __restrict__ base,
    const float* __restrict__ mid, const short* __restrict__ Aeff,
    float* __restrict__ out) {
  const int token = blockIdx.x;
  const int chunk = token >> 6;
  __shared__ float m[16];
  if (threadIdx.x < 16) m[threadIdx.x] = mid[(long)token * 16 + threadIdx.x];
  __syncthreads();
  float mf[16];
  #pragma unroll
  for (int r = 0; r < 16; ++r) mf[r] = m[r];
  for (int it = 0; it < 2; ++it) {
    const int h0 = it * 2048 + threadIdx.x * 8;
    bf16x8 bs = *(const bf16x8*)(base + (long)token * 4096 + h0);
    float res[8];
    #pragma unroll
    for (int j = 0; j < 8; ++j) {
      const short* ar = Aeff + ((long)chunk * 4096 + h0 + j) * 16;
      bf16x8 a0 = *(const bf16x8*)ar;
      bf16x8 a1 = *(const bf16x8*)(ar + 8);
      float s = 0.f;
      #pragma unroll
      for (int r = 0; r < 8; ++r) {
        s = fmaf(mf[r], b2f(a0[r]), s);
        s = fmaf(mf[r + 8], b2f(a1[r]), s);
      }
      res[j] = b2f(bs[j]) + 2.0f * s;
    }
    #pragma unroll
    for (int i = 0; i < 2; ++i) {
      f32x4 w; w[0] = res[i*4]; w[1] = res[i*4+1]; w[2] = res[i*4+2]; w[3] = res[i*4+3];
      *(f32x4*)(out + (long)token * 4096 + h0 + i * 4) = w;
    }
  }
}

extern "C" void kernel_launch(void* const* d_in, const int* in_sizes, int n_in,
                              void* d_out, int out_size, void* d_ws, size_t ws_size,
                              hipStream_t stream) {
  const float* x     = (const float*)d_in[0];   // [2,2048,11008]
  const float* Wbase = (const float*)d_in[1];   // [4096,11008]
  const float* emb   = (const float*)d_in[2];   // [32000,4096]
  const float* Wproj = (const float*)d_in[3];   // [4096,4096]
  const float* initA = (const float*)d_in[4];   // [4096,16]
  const float* initB = (const float*)d_in[5];   // [16,11008]
  const int*   ids   = (const int*)d_in[6];     // [2,2048]
  float* outp = (float*)d_out;                  // f32 [2,2048,4096]

  char* p = (char*)d_ws;
  short* xb   = (short*)p; p += 90177536L;   // x bf16
  short* Wb   = (short*)p; p += 90177536L;   // W_base bf16
  short* Wpb  = (short*)p; p += 33554432L;   // W_proj bf16 (dead after V GEMM)
  short* shb  = (short*)p; p += 33554432L;   // shifted embeds bf16 (dead after V GEMM)
  short* Vb   = (short*)p; p += 33554432L;   // V bf16
  short* base = (short*)p; p += 33554432L;   // base_out bf16
  short* iBb  = (short*)p; p += 352256L;     // init_B bf16
  short* iAt  = (short*)p; p += 131072L;     // init_A^T bf16 [16][4096]
  float* pin  = (float*)p; p += 262144L;     // proj_in f32 [4096][16]
  float* per  = (float*)p; p += 262144L;     // proj_err f32 [4096][16]
  float* mid  = (float*)p; p += 262144L;     // mid f32 [4096][16]
  short* Aeff = (short*)p; p += 8388608L;    // [64][4096][16] bf16
  short* Beff = (short*)p; p += 22544384L;   // [64][16][11008] bf16
  // dA/dB alias Wpb+shb (live only after V GEMM): 16MB + 45MB < 64MB
  float* dA = (float*)Wpb;
  float* dB = (float*)((char*)Wpb + 16777216L);

  cvt_kernel<<<2048, 256, 0, stream>>>(x, xb, 45088768L);
  cvt_kernel<<<2048, 256, 0, stream>>>(Wbase, Wb, 45088768L);
  cvt_kernel<<<2048, 256, 0, stream>>>(Wproj, Wpb, 16777216L);
  cvt_kernel<<<86, 256, 0, stream>>>(initB, iBb, 176128L);
  tposeA_kernel<<<16, 256, 0, stream>>>(initA, iAt);
  gather_kernel<<<4096, 256, 0, stream>>>(emb, ids, shb);

  gemm8p<1><<<256, 512, 0, stream>>>(shb, Wpb, (void*)Vb, 4096, 4096, 4096);
  gemm8p<1><<<256, 512, 0, stream>>>(xb, Wb, (void*)base, 4096, 4096, 11008);

  rowgemm16<<<1024, 256, 0, stream>>>(xb, iBb, pin, 11008, 0L);   // proj_in
  rowgemm16<<<1024, 256, 0, stream>>>(Vb, iAt, per, 4096, 0L);    // proj_err

  dA_kernel<<<dim3(16, 64), 256, 0, stream>>>(Vb, pin, dA);
  dB_kernel<<<dim3(43, 64), 256, 0, stream>>>(xb, per, dB);
  scanA_kernel<<<dim3(256, 2), 256, 0, stream>>>(dA, initA, Aeff);
  scanB_kernel<<<dim3(688, 2), 256, 0, stream>>>(dB, initB, Beff);

  rowgemm16<<<1024, 256, 0, stream>>>(xb, Beff, mid, 11008, 176128L);  // mid
  final_kernel<<<4096, 256, 0, stream>>>(base, mid, Aeff, outp);
}

// Round 6
// 889.792 us; speedup vs baseline: 2.7018x; 1.0110x over previous
//
#include <hip/hip_runtime.h>

typedef __attribute__((ext_vector_type(8))) short bf16x8;
typedef __attribute__((ext_vector_type(4))) float f32x4;

__device__ __forceinline__ float b2f(short s) {
  return __uint_as_float(((unsigned int)(unsigned short)s) << 16);
}
__device__ __forceinline__ short f2b(float f) {
  unsigned int u = __float_as_uint(f);
  unsigned int r = (u + 0x7fffu + ((u >> 16) & 1u)) >> 16;
  return (short)(unsigned short)r;
}

#define GLOAD16(g, l) __builtin_amdgcn_global_load_lds( \
    (const __attribute__((address_space(1))) void*)(g),  \
    (__attribute__((address_space(3))) void*)(l), 16, 0, 0)

// ---------------- f32 -> bf16 convert ----------------
__global__ __launch_bounds__(256) void cvt_kernel(const float* __restrict__ src,
                                                  short* __restrict__ dst, long n) {
  long i = ((long)blockIdx.x * 256 + threadIdx.x) * 8;
  long stride = (long)gridDim.x * 256 * 8;
  for (; i + 8 <= n; i += stride) {
    float4 a = *(const float4*)(src + i);
    float4 b = *(const float4*)(src + i + 4);
    bf16x8 o;
    o[0] = f2b(a.x); o[1] = f2b(a.y); o[2] = f2b(a.z); o[3] = f2b(a.w);
    o[4] = f2b(b.x); o[5] = f2b(b.y); o[6] = f2b(b.z); o[7] = f2b(b.w);
    *(bf16x8*)(dst + i) = o;
  }
}

// ---------------- gather next-token embeddings, shift, convert ----------------
__global__ __launch_bounds__(256) void gather_kernel(const float* __restrict__ emb,
    const int* __restrict__ ids, short* __restrict__ sh) {
  const int token = blockIdx.x;          // 0..4095, token = b*2048 + s
  const int s = token & 2047;
  const long dst = (long)token * 4096;
  const int row = (s == 2047) ? -1 : ids[token + 1];
  for (int it = 0; it < 2; ++it) {
    const int e = it * 2048 + threadIdx.x * 8;
    bf16x8 o;
    if (row < 0) {
      #pragma unroll
      for (int j = 0; j < 8; ++j) o[j] = 0;
    } else {
      float4 a = *(const float4*)(emb + (long)row * 4096 + e);
      float4 b = *(const float4*)(emb + (long)row * 4096 + e + 4);
      o[0] = f2b(a.x); o[1] = f2b(a.y); o[2] = f2b(a.z); o[3] = f2b(a.w);
      o[4] = f2b(b.x); o[5] = f2b(b.y); o[6] = f2b(b.z); o[7] = f2b(b.w);
    }
    *(bf16x8*)(sh + dst + e) = o;
  }
}

// ---------------- init_A [4096][16] f32 -> [16][4096] bf16 ----------------
__global__ __launch_bounds__(256) void tposeA_kernel(const float* __restrict__ A,
                                                     short* __restrict__ At) {
  const int h = blockIdx.x * 256 + threadIdx.x;
  #pragma unroll
  for (int r = 0; r < 16; ++r) At[(long)r * 4096 + h] = f2b(A[(long)h * 16 + r]);
}

// ======== deep-pipelined 256x256 MFMA GEMM: C[M,N] = A[M,K] @ B[N,K]^T ========
// Round-6 change: ds_reads software-pipelined one phase ahead (ping-pong
// avX/avY), counted lgkmcnt(4) per phase; B-frags + next chunk0 prefetched at
// q3 after vmcnt(6)+barrier (collective LDS validity) and after MFMA q3
// (register WAR), pinned by sched_barrier(0). Staging/vmcnt identical to r5.
template <int OUTBF16>
__global__ __launch_bounds__(512, 2) void gemm8p(const short* __restrict__ A,
    const short* __restrict__ B, void* __restrict__ C, int M, int N, int Kd) {
  __shared__ short lds[65536];  // 128 KiB: buf{0,1} x [A 32K | B 32K]
  const int tid = threadIdx.x;
  const int lane = tid & 63;
  const int wid = tid >> 6;        // 0..7
  const int wr = wid >> 2;         // 0..1  (M half)
  const int wcn = wid & 3;         // 0..3  (N quarter)
  const int l15 = lane & 15, l4 = lane >> 4, l7 = lane & 7;
  const int lb = (lane >> 3) & 1;

  const int nbx = N >> 8;
  const int cpx = gridDim.x >> 3;
  const int wg = ((int)blockIdx.x & 7) * cpx + ((int)blockIdx.x >> 3);
  const long m0 = (long)(wg / nbx) * 256;
  const long n0 = (long)(wg % nbx) * 256;

  const int NT = Kd >> 6;

  const int rho = lane >> 3;
  const short* Ag = A + (m0 + wid * 8 + rho) * (long)Kd + (l7 ^ rho) * 8;
  const short* Bg = B + (n0 + wid * 8 + rho) * (long)Kd + (l7 ^ rho) * 8;

#define STAGE_A(b, kt, c) GLOAD16(Ag + (long)(c) * 64 * Kd + (long)(kt) * 64, \
    (char*)lds + (b) * 65536 + ((c) * 8 + wid) * 1024 + lane * 16)
#define STAGE_B(b, kt, c) GLOAD16(Bg + (long)(c) * 64 * Kd + (long)(kt) * 64, \
    (char*)lds + (b) * 65536 + 32768 + ((c) * 8 + wid) * 1024 + lane * 16)

  int aLane[2];
  #pragma unroll
  for (int h = 0; h < 2; ++h)
    aLane[h] = (lb * 64 + l7 * 8 + ((h * 4 + l4) ^ l7)) * 16;

#define READ_A(dst, buf, c)                                                   \
  do {                                                                        \
    _Pragma("unroll")                                                         \
    for (int sub = 0; sub < 2; ++sub) {                                       \
      dst[sub][0] = *(const bf16x8*)((buf) + (c) * 8192 + wr * 4096 +         \
                                     sub * 2048 + aLane[0]);                  \
      dst[sub][1] = *(const bf16x8*)((buf) + (c) * 8192 + wr * 4096 +         \
                                     sub * 2048 + aLane[1]);                  \
    }                                                                         \
  } while (0)

#define READ_B(buf)                                                           \
  do {                                                                        \
    _Pragma("unroll")                                                         \
    for (int nf = 0; nf < 4; ++nf) {                                          \
      bv[nf][0] = *(const bf16x8*)((buf) + 32768 + wcn * 8192 + nf * 2048 +   \
                                   aLane[0]);                                 \
      bv[nf][1] = *(const bf16x8*)((buf) + 32768 + wcn * 8192 + nf * 2048 +   \
                                   aLane[1]);                                 \
    }                                                                         \
  } while (0)

#define MFMA_BLOCK(q, av)                                                     \
  do {                                                                        \
    _Pragma("unroll")                                                         \
    for (int sub = 0; sub < 2; ++sub)                                         \
      _Pragma("unroll")                                                       \
      for (int nf = 0; nf < 4; ++nf) {                                        \
        acc[(q) * 2 + sub][nf] = __builtin_amdgcn_mfma_f32_16x16x32_bf16(     \
            av[sub][0], bv[nf][0], acc[(q) * 2 + sub][nf], 0, 0, 0);          \
        acc[(q) * 2 + sub][nf] = __builtin_amdgcn_mfma_f32_16x16x32_bf16(     \
            av[sub][1], bv[nf][1], acc[(q) * 2 + sub][nf], 0, 0, 0);          \
      }                                                                       \
  } while (0)

  f32x4 acc[8][4];
  #pragma unroll
  for (int m = 0; m < 8; ++m)
    #pragma unroll
    for (int n = 0; n < 4; ++n) {
      acc[m][n][0] = 0.f; acc[m][n][1] = 0.f;
      acc[m][n][2] = 0.f; acc[m][n][3] = 0.f;
    }

  // -------- prologue: tile0 (8 chunk-pairs) + tile1 chunks 0..2 --------
  STAGE_A(0, 0, 0); STAGE_B(0, 0, 0);
  STAGE_A(0, 0, 1); STAGE_B(0, 0, 1);
  STAGE_A(0, 0, 2); STAGE_B(0, 0, 2);
  STAGE_A(0, 0, 3); STAGE_B(0, 0, 3);
  STAGE_A(1, 1, 0); STAGE_B(1, 1, 0);
  STAGE_A(1, 1, 1); STAGE_B(1, 1, 1);
  STAGE_A(1, 1, 2); STAGE_B(1, 1, 2);
  asm volatile("s_waitcnt vmcnt(6)" ::: "memory");
  __builtin_amdgcn_s_barrier();
  asm volatile("" ::: "memory");

  const char* ldsb = (const char*)lds;
  bf16x8 avX[2][2], avY[2][2], bv[4][2];
  READ_B(ldsb);
  READ_A(avX, ldsb, 0);

  for (int t = 0; t < NT; ++t) {
    const int cur = t & 1;
    const int tn1 = (t + 1 < NT) ? t + 1 : 0;   // wrap -> garbage stage/read, safe
    const int tn2 = (t + 2 < NT) ? t + 2 : 0;
    const char* pc = ldsb + cur * 65536;
    const char* pn = ldsb + (cur ^ 1) * 65536;

    // ---- phase 0: prefetch ch1 -> avY; MFMA ch0 (avX) ----
    READ_A(avY, pc, 1);
    STAGE_A(cur ^ 1, tn1, 3); STAGE_B(cur ^ 1, tn1, 3);
    __builtin_amdgcn_s_barrier();
    asm volatile("s_waitcnt lgkmcnt(4)" ::: "memory");
    __builtin_amdgcn_sched_barrier(0);
    __builtin_amdgcn_s_setprio(1);
    MFMA_BLOCK(0, avX);
    __builtin_amdgcn_s_setprio(0);
    __builtin_amdgcn_s_barrier();
    asm volatile("" ::: "memory");

    // ---- phase 1: prefetch ch2 -> avX; MFMA ch1 (avY) ----
    READ_A(avX, pc, 2);
    STAGE_A(cur, tn2, 0); STAGE_B(cur, tn2, 0);
    __builtin_amdgcn_s_barrier();
    asm volatile("s_waitcnt lgkmcnt(4)" ::: "memory");
    __builtin_amdgcn_sched_barrier(0);
    __builtin_amdgcn_s_setprio(1);
    MFMA_BLOCK(1, avY);
    __builtin_amdgcn_s_setprio(0);
    __builtin_amdgcn_s_barrier();
    asm volatile("" ::: "memory");

    // ---- phase 2: prefetch ch3 -> avY; MFMA ch2 (avX) ----
    READ_A(avY, pc, 3);
    STAGE_A(cur, tn2, 1); STAGE_B(cur, tn2, 1);
    __builtin_amdgcn_s_barrier();
    asm volatile("s_waitcnt lgkmcnt(4)" ::: "memory");
    __builtin_amdgcn_sched_barrier(0);
    __builtin_amdgcn_s_setprio(1);
    MFMA_BLOCK(2, avX);
    __builtin_amdgcn_s_setprio(0);
    __builtin_amdgcn_s_barrier();
    asm volatile("" ::: "memory");

    // ---- phase 3: MFMA ch3 (avY); then prefetch next tile B + ch0 -> avX ----
    STAGE_A(cur, tn2, 2); STAGE_B(cur, tn2, 2);
    asm volatile("s_waitcnt vmcnt(6)" ::: "memory");
    __builtin_amdgcn_s_barrier();
    asm volatile("s_waitcnt lgkmcnt(0)" ::: "memory");
    __builtin_amdgcn_sched_barrier(0);
    __builtin_amdgcn_s_setprio(1);
    MFMA_BLOCK(3, avY);
    __builtin_amdgcn_s_setprio(0);
    __builtin_amdgcn_sched_barrier(0);
    READ_B(pn);
    READ_A(avX, pn, 0);
    __builtin_amdgcn_s_barrier();
    asm volatile("" ::: "memory");
  }
#undef STAGE_A
#undef STAGE_B
#undef READ_A
#undef READ_B
#undef MFMA_BLOCK

  // -------- epilogue: C write --------
  #pragma unroll
  for (int q = 0; q < 4; ++q)
    #pragma unroll
    for (int sub = 0; sub < 2; ++sub)
      #pragma unroll
      for (int nf = 0; nf < 4; ++nf)
        #pragma unroll
        for (int j = 0; j < 4; ++j) {
          const long row = m0 + q * 64 + wr * 32 + sub * 16 + l4 * 4 + j;
          const long col = n0 + wcn * 64 + nf * 16 + l15;
          if (OUTBF16) ((short*)C)[row * N + col] = f2b(acc[q * 2 + sub][nf][j]);
          else         ((float*)C)[row * N + col] = acc[q * 2 + sub][nf][j];
        }
}

// ---------------- skinny GEMM: out[t][16] = X[t,:] @ W[16,K]^T ----------------
__global__ __launch_bounds__(256) void rowgemm16(const short* __restrict__ X,
    const short* __restrict__ W, float* __restrict__ out, int K, long wStride) {
  const int lane = threadIdx.x & 63;
  const int token = blockIdx.x * 4 + (threadIdx.x >> 6);
  const short* Xr = X + (long)token * K;
  const short* Wr = W + (long)(token >> 6) * wStride;
  float acc[16];
  #pragma unroll
  for (int r = 0; r < 16; ++r) acc[r] = 0.f;
  const int nIter = (K + 511) >> 9;
  for (int i = 0; i < nIter; ++i) {
    const int k = i * 512 + lane * 8;
    if (k + 8 <= K) {
      bf16x8 xv = *(const bf16x8*)(Xr + k);
      float xf[8];
      #pragma unroll
      for (int j = 0; j < 8; ++j) xf[j] = b2f(xv[j]);
      #pragma unroll
      for (int r = 0; r < 16; ++r) {
        bf16x8 wv = *(const bf16x8*)(Wr + (long)r * K + k);
        #pragma unroll
        for (int j = 0; j < 8; ++j) acc[r] = fmaf(xf[j], b2f(wv[j]), acc[r]);
      }
    }
  }
  #pragma unroll
  for (int r = 0; r < 16; ++r) {
    float v = acc[r];
    #pragma unroll
    for (int off = 32; off > 0; off >>= 1) v += __shfl_xor(v, off, 64);
    acc[r] = v;
  }
  if (lane == 0) {
    #pragma unroll
    for (int r = 0; r < 16; ++r) out[(long)token * 16 + r] = acc[r];
  }
}

// ---------------- pass 1a: dA[chunk][h][r] = sum_c V[c,h]*pin[c,r] ----------------
__global__ __launch_bounds__(256) void dA_kernel(const short* __restrict__ V,
    const float* __restrict__ pin, float* __restrict__ dA) {
  const int chunk = blockIdx.y;
  const int h = blockIdx.x * 256 + threadIdx.x;
  __shared__ float ps[1024];
  #pragma unroll
  for (int i = 0; i < 4; ++i)
    ps[i * 256 + threadIdx.x] = pin[(long)chunk * 1024 + i * 256 + threadIdx.x];
  __syncthreads();
  float acc[16];
  #pragma unroll
  for (int r = 0; r < 16; ++r) acc[r] = 0.f;
  for (int c = 0; c < 64; ++c) {
    const float v = b2f(V[((long)chunk * 64 + c) * 4096 + h]);
    #pragma unroll
    for (int r = 0; r < 16; ++r) acc[r] = fmaf(v, ps[c * 16 + r], acc[r]);
  }
  float* dst = dA + ((long)chunk * 4096 + h) * 16;
  #pragma unroll
  for (int i = 0; i < 4; ++i) {
    f32x4 w; w[0] = acc[i*4]; w[1] = acc[i*4+1]; w[2] = acc[i*4+2]; w[3] = acc[i*4+3];
    *(f32x4*)(dst + i * 4) = w;
  }
}

// ---------------- pass 1b: dB[chunk][r][k] = sum_c per[c,r]*X[c,k] ----------------
__global__ __launch_bounds__(256) void dB_kernel(const short* __restrict__ X,
    const float* __restrict__ per, float* __restrict__ dB) {
  const int chunk = blockIdx.y;
  const int k = blockIdx.x * 256 + threadIdx.x;   // 43*256 == 11008
  __shared__ float ps[1024];
  #pragma unroll
  for (int i = 0; i < 4; ++i)
    ps[i * 256 + threadIdx.x] = per[(long)chunk * 1024 + i * 256 + threadIdx.x];
  __syncthreads();
  float acc[16];
  #pragma unroll
  for (int r = 0; r < 16; ++r) acc[r] = 0.f;
  for (int c = 0; c < 64; ++c) {
    const float xv = b2f(X[((long)chunk * 64 + c) * 11008 + k]);
    #pragma unroll
    for (int r = 0; r < 16; ++r) acc[r] = fmaf(xv, ps[c * 16 + r], acc[r]);
  }
  #pragma unroll
  for (int r = 0; r < 16; ++r)
    dB[((long)chunk * 16 + r) * 11008 + k] = acc[r];
}

// ---------- pass 2a: exclusive scan over chunks -> A_eff bf16 ----------
__global__ __launch_bounds__(256) void scanA_kernel(const float* __restrict__ dA,
    const float* __restrict__ initA, short* __restrict__ Aeff) {
  const int b = blockIdx.y;
  const long idx = (long)blockIdx.x * 256 + threadIdx.x;  // h*16+r, < 65536
  const float a0 = initA[idx];
  float acc = 0.f;
  for (int n = 0; n < 32; ++n) {
    const long chunk = (long)b * 32 + n;
    Aeff[chunk * 65536 + idx] = f2b(a0 - 0.02f * acc);
    acc += dA[chunk * 65536 + idx];
  }
}

// ---------- pass 2b: exclusive scan over chunks -> B_eff bf16 ----------
__global__ __launch_bounds__(256) void scanB_kernel(const float* __restrict__ dB,
    const float* __restrict__ initB, short* __restrict__ Beff) {
  const int b = blockIdx.y;
  const long idx = (long)blockIdx.x * 256 + threadIdx.x;  // r*11008+k, < 176128
  const float b0 = initB[idx];
  float acc = 0.f;
  for (int n = 0; n < 32; ++n) {
    const long chunk = (long)b * 32 + n;
    Beff[chunk * 176128 + idx] = f2b(b0 - 0.02f * acc);
    acc += dB[chunk * 176128 + idx];
  }
}

// ---------------- out(f32) = base(bf16) + 2 * mid @ A_eff^T ----------------
__global__ __launch_bounds__(256) void final_kernel(const short* __restrict__ base,
    const float* __restrict__ mid, const short* __restrict__ Aeff,
    float* __restrict__ out) {
  const int token = blockIdx.x;
  const int chunk = token >> 6;
  __shared__ float m[16];
  if (threadIdx.x < 16) m[threadIdx.x] = mid[(long)token * 16 + threadIdx.x];
  __syncthreads();
  float mf[16];
  #pragma unroll
  for (int r = 0; r < 16; ++r) mf[r] = m[r];
  for (int it = 0; it < 2; ++it) {
    const int h0 = it * 2048 + threadIdx.x * 8;
    bf16x8 bs = *(const bf16x8*)(base + (long)token * 4096 + h0);
    float res[8];
    #pragma unroll
    for (int j = 0; j < 8; ++j) {
      const short* ar = Aeff + ((long)chunk * 4096 + h0 + j) * 16;
      bf16x8 a0 = *(const bf16x8*)ar;
      bf16x8 a1 = *(const bf16x8*)(ar + 8);
      float s = 0.f;
      #pragma unroll
      for (int r = 0; r < 8; ++r) {
        s = fmaf(mf[r], b2f(a0[r]), s);
        s = fmaf(mf[r + 8], b2f(a1[r]), s);
      }
      res[j] = b2f(bs[j]) + 2.0f * s;
    }
    #pragma unroll
    for (int i = 0; i < 2; ++i) {
      f32x4 w; w[0] = res[i*4]; w[1] = res[i*4+1]; w[2] = res[i*4+2]; w[3] = res[i*4+3];
      *(f32x4*)(out + (long)token * 4096 + h0 + i * 4) = w;
    }
  }
}

extern "C" void kernel_launch(void* const* d_in, const int* in_sizes, int n_in,
                              void* d_out, int out_size, void* d_ws, size_t ws_size,
                              hipStream_t stream) {
  const float* x     = (const float*)d_in[0];   // [2,2048,11008]
  const float* Wbase = (const float*)d_in[1];   // [4096,11008]
  const float* emb   = (const float*)d_in[2];   // [32000,4096]
  const float* Wproj = (const float*)d_in[3];   // [4096,4096]
  const float* initA = (const float*)d_in[4];   // [4096,16]
  const float* initB = (const float*)d_in[5];   // [16,11008]
  const int*   ids   = (const int*)d_in[6];     // [2,2048]
  float* outp = (float*)d_out;                  // f32 [2,2048,4096]

  char* p = (char*)d_ws;
  short* xb   = (short*)p; p += 90177536L;   // x bf16
  short* Wb   = (short*)p; p += 90177536L;   // W_base bf16
  short* Wpb  = (short*)p; p += 33554432L;   // W_proj bf16 (dead after V GEMM)
  short* shb  = (short*)p; p += 33554432L;   // shifted embeds bf16 (dead after V GEMM)
  short* Vb   = (short*)p; p += 33554432L;   // V bf16
  short* base = (short*)p; p += 33554432L;   // base_out bf16
  short* iBb  = (short*)p; p += 352256L;     // init_B bf16
  short* iAt  = (short*)p; p += 131072L;     // init_A^T bf16 [16][4096]
  float* pin  = (float*)p; p += 262144L;     // proj_in f32 [4096][16]
  float* per  = (float*)p; p += 262144L;     // proj_err f32 [4096][16]
  float* mid  = (float*)p; p += 262144L;     // mid f32 [4096][16]
  short* Aeff = (short*)p; p += 8388608L;    // [64][4096][16] bf16
  short* Beff = (short*)p; p += 22544384L;   // [64][16][11008] bf16
  // dA/dB alias Wpb+shb (live only after V GEMM): 16MB + 45MB < 64MB
  float* dA = (float*)Wpb;
  float* dB = (float*)((char*)Wpb + 16777216L);

  cvt_kernel<<<2048, 256, 0, stream>>>(x, xb, 45088768L);
  cvt_kernel<<<2048, 256, 0, stream>>>(Wbase, Wb, 45088768L);
  cvt_kernel<<<2048, 256, 0, stream>>>(Wproj, Wpb, 16777216L);
  cvt_kernel<<<86, 256, 0, stream>>>(initB, iBb, 176128L);
  tposeA_kernel<<<16, 256, 0, stream>>>(initA, iAt);
  gather_kernel<<<4096, 256, 0, stream>>>(emb, ids, shb);

  gemm8p<1><<<256, 512, 0, stream>>>(shb, Wpb, (void*)Vb, 4096, 4096, 4096);
  gemm8p<1><<<256, 512, 0, stream>>>(xb, Wb, (void*)base, 4096, 4096, 11008);

  rowgemm16<<<1024, 256, 0, stream>>>(xb, iBb, pin, 11008, 0L);   // proj_in
  rowgemm16<<<1024, 256, 0, stream>>>(Vb, iAt, per, 4096, 0L);    // proj_err

  dA_kernel<<<dim3(16, 64), 256, 0, stream>>>(Vb, pin, dA);
  dB_kernel<<<dim3(43, 64), 256, 0, stream>>>(xb, per, dB);
  scanA_kernel<<<dim3(256, 2), 256, 0, stream>>>(dA, initA, Aeff);
  scanB_kernel<<<dim3(688, 2), 256, 0, stream>>>(dB, initB, Beff);

  rowgemm16<<<1024, 256, 0, stream>>>(xb, Beff, mid, 11008, 176128L);  // mid
  final_kernel<<<4096, 256, 0, stream>>>(base, mid, Aeff, outp);
}